// Round 3
// baseline (385.221 us; speedup 1.0000x reference)
//
#include <hip/hip_runtime.h>
#include <stdint.h>

typedef __bf16 bf16x8 __attribute__((ext_vector_type(8)));
typedef float f32x4 __attribute__((ext_vector_type(4)));
typedef unsigned short ushort_t;

#define N_OUT 11008
#define K_DIM 4096
#define M_DIM 512
#define BM 256
#define BN 64
#define BK 64
#define KHALF 2048
#define NT 32 /* KHALF / BK */
#define BSTRIDE (BN * 72)

__constant__ float c_nf4[16] = {
    -1.0f, -0.6961928009986877f, -0.5250730514526367f, -0.39491748809814453f,
    -0.28444138169288635f, -0.18477343022823334f, -0.09105003625154495f, 0.0f,
    0.07958029955625534f, 0.16093020141124725f, 0.24611230194568634f,
    0.33791524171829224f, 0.44070982933044434f, 0.5626170039176941f,
    0.7229568362236023f, 1.0f};

// round-half-up fp32 -> bf16, pack two into u32
__device__ __forceinline__ uint32_t pkbf(float lo, float hi) {
  uint32_t ul = __builtin_bit_cast(uint32_t, lo);
  uint32_t uh = __builtin_bit_cast(uint32_t, hi);
  return ((ul + 0x8000u) >> 16) | ((uh + 0x8000u) & 0xffff0000u);
}

__device__ __forceinline__ void async16(const void* g, void* l) {
  __builtin_amdgcn_global_load_lds(
      (const __attribute__((address_space(1))) void*)g,
      (__attribute__((address_space(3))) void*)l, 16, 0, 0);
}

__device__ __forceinline__ bf16x8 ldfrag(const ushort_t* p) {
  uint4 r = *reinterpret_cast<const uint4*>(p);
  return __builtin_bit_cast(bf16x8, r);
}

__device__ __forceinline__ uint32_t dq2(int a, int b, float s, const float2* lut) {
  float2 l = lut[a | (b << 4)];
  return pkbf(l.x * s, l.y * s);
}

// =============== fused prep: cvt+swizzle | x@A | B^T | bias-init =============
// grid: [0,1024) cvt, [1024,1536) xa, [1536,1579) bt, [1579,7083) bias-init
__global__ void k_prep(const float* __restrict__ x, const float* __restrict__ lA,
                       const float* __restrict__ lB, const float* __restrict__ bias,
                       ushort_t* __restrict__ xbf, ushort_t* __restrict__ xap,
                       ushort_t* __restrict__ btp, float* __restrict__ out) {
  const int b = blockIdx.x, t = threadIdx.x;
  if (b < 1024) {
    // x fp32 -> bf16 with XOR chunk swizzle inside each 64-elem k-window:
    // stored chunk position cp holds original chunk cp ^ (m&7)
    int oc = b * 256 + t;          // 16B output chunk id (8 bf16)
    int m = oc >> 9;               // 512 chunks per row
    int cr = oc & 511;
    int win = cr >> 3, cp = cr & 7;
    int c = cp ^ (m & 7);
    const float4* s4 = (const float4*)(x + (size_t)m * K_DIM + win * 64 + c * 8);
    float4 v0 = s4[0], v1 = s4[1];
    uint4 o;
    o.x = pkbf(v0.x, v0.y);
    o.y = pkbf(v0.z, v0.w);
    o.z = pkbf(v1.x, v1.y);
    o.w = pkbf(v1.z, v1.w);
    ((uint4*)xbf)[oc] = o;
  } else if (b < 1536) {
    // xa = 2*(x @ lora_A) for one row m, padded [512,32] bf16
    __shared__ float red[256 * 17];
    int m = b - 1024;
    int ks = t * 16;
    alignas(16) float xs[16];
    const f32x4* xv = (const f32x4*)(x + (size_t)m * K_DIM + ks);
    ((f32x4*)xs)[0] = xv[0];
    ((f32x4*)xs)[1] = xv[1];
    ((f32x4*)xs)[2] = xv[2];
    ((f32x4*)xs)[3] = xv[3];
    f32x4 ac0 = 0.f, ac1 = 0.f, ac2 = 0.f, ac3 = 0.f;
#pragma unroll
    for (int kk = 0; kk < 16; ++kk) {
      float xk = xs[kk];
      const f32x4* l4 = (const f32x4*)(lA + (size_t)(ks + kk) * 16);
      ac0 += xk * l4[0];
      ac1 += xk * l4[1];
      ac2 += xk * l4[2];
      ac3 += xk * l4[3];
    }
#pragma unroll
    for (int r = 0; r < 4; ++r) {
      red[t * 17 + r] = ac0[r];
      red[t * 17 + 4 + r] = ac1[r];
      red[t * 17 + 8 + r] = ac2[r];
      red[t * 17 + 12 + r] = ac3[r];
    }
    __syncthreads();
#pragma unroll
    for (int s = 128; s >= 16; s >>= 1) {
      if (t < s)
        for (int r = 0; r < 16; ++r) red[t * 17 + r] += red[(t + s) * 17 + r];
      __syncthreads();
    }
    if (t < 32) {
      float v = 0.f;
      if (t < 16) {
        for (int p = 0; p < 16; ++p) v += red[p * 17 + t];
        v *= 2.0f;  // SCALING
      }
      uint32_t u = __builtin_bit_cast(uint32_t, v);
      xap[(size_t)m * 32 + t] = (ushort_t)((u + 0x8000u) >> 16);
    }
  } else if (b < 1579) {
    // Bt = lora_B^T, padded [11008,32] bf16
    int o = (b - 1536) * 256 + t;
    uint32_t p[8];
#pragma unroll
    for (int j = 0; j < 8; ++j)
      p[j] = pkbf(lB[(size_t)(2 * j) * N_OUT + o], lB[(size_t)(2 * j + 1) * N_OUT + o]);
    uint4* dst = reinterpret_cast<uint4*>(btp + (size_t)o * 32);
    dst[0] = make_uint4(p[0], p[1], p[2], p[3]);
    dst[1] = make_uint4(p[4], p[5], p[6], p[7]);
    dst[2] = make_uint4(0u, 0u, 0u, 0u);
    dst[3] = make_uint4(0u, 0u, 0u, 0u);
  } else {
    // out = broadcast bias (split-K blocks atomically add on top)
    int i = (b - 1579) * 256 + t;  // float4 id, 1,409,024 total
    int col4 = i % 2752;           // 11008/4
    ((float4*)out)[i] = ((const float4*)bias)[col4];
  }
}

// ---------------- one K-tile, dequant software-pipelined ----------------
// Steady-state FIFO entering tile kt:
//   [ idx(kt+1) x5, DMA_A(kt) x8, idx(kt+2) x5 ]  (bi regs hold idx(kt+1))
// vmcnt(5): drains idx(kt+1)+DMA_A(kt) -> A in LDS, dequant inputs ready,
// idx(kt+2) stays in flight. Tile body: kc0 frags+MFMA -> kc1 frags ->
// lgkm(0) (lds_a reusable) -> issue DMA_A(kt+1) -> kc1 MFMA -> dequant(kt+1)
// into b[pb^1] (hidden behind MFMA pipe drain) -> refill idx(kt+3) ->
// lgkm(0) -> raw barrier (vmcnt NOT drained). One barrier per tile.
__device__ __forceinline__ void tile_step(
    int kt, int4 (&bi)[4], float& s, const float2* lutp, ushort_t* lb,
    const ushort_t* bfb, const ushort_t* afb, const ushort_t* ga,
    ushort_t* la_dst, const int* gb0, const float* gs, int lane, int q,
    f32x4 (&acc)[4][4]) {
  const int pb = kt & 1;
  asm volatile("s_waitcnt vmcnt(5)" ::: "memory");  // A(kt)+idx(kt+1) landed
  const ushort_t* bfbk = bfb + pb * BSTRIDE;
  {  // kc = 0
    const int cpr = (q ^ (lane & 7)) * 8;
    bf16x8 av[4], bv[4];
#pragma unroll
    for (int mi = 0; mi < 4; ++mi) av[mi] = ldfrag(afb + mi * 16 * BK + cpr);
#pragma unroll
    for (int ni = 0; ni < 4; ++ni) bv[ni] = ldfrag(bfbk + ni * 16 * 72);
#pragma unroll
    for (int mi = 0; mi < 4; ++mi)
#pragma unroll
      for (int ni = 0; ni < 4; ++ni)
        acc[mi][ni] = __builtin_amdgcn_mfma_f32_16x16x32_bf16(av[mi], bv[ni],
                                                              acc[mi][ni], 0, 0, 0);
  }
  // kc = 1 fragment reads
  bf16x8 av1[4], bv1[4];
  {
    const int cpr = ((4 + q) ^ (lane & 7)) * 8;
#pragma unroll
    for (int mi = 0; mi < 4; ++mi) av1[mi] = ldfrag(afb + mi * 16 * BK + cpr);
#pragma unroll
    for (int ni = 0; ni < 4; ++ni) bv1[ni] = ldfrag(bfbk + ni * 16 * 72 + 32);
  }
  asm volatile("s_waitcnt lgkmcnt(0)" ::: "memory");  // all 16 frag reads done
  __builtin_amdgcn_sched_barrier(0);
  // A-DMA for tile kt+1 (at kt=NT-1 the over-read stays inside the workspace;
  // the garbage LDS write is drained by vmcnt(0) before the tail reuses lds_a)
#pragma unroll
  for (int j = 0; j < 8; ++j)
    async16(ga + (size_t)j * 8 * K_DIM + (size_t)(kt + 1) * BK, la_dst + j * 512);
  __builtin_amdgcn_sched_barrier(0);
  // kc = 1 MFMA (matrix pipe stays busy ~80cy while the wave runs dequant)
#pragma unroll
  for (int mi = 0; mi < 4; ++mi)
#pragma unroll
    for (int ni = 0; ni < 4; ++ni)
      acc[mi][ni] = __builtin_amdgcn_mfma_f32_16x16x32_bf16(av1[mi], bv1[ni],
                                                            acc[mi][ni], 0, 0, 0);
  __builtin_amdgcn_sched_barrier(0);
  // dequant tile kt+1 -> b[pb^1] (inputs already landed: no vmem wait here)
  uint4 w0, w1;
  w0.x = dq2(bi[0].x, bi[0].y, s, lutp);
  w0.y = dq2(bi[0].z, bi[0].w, s, lutp);
  w0.z = dq2(bi[1].x, bi[1].y, s, lutp);
  w0.w = dq2(bi[1].z, bi[1].w, s, lutp);
  w1.x = dq2(bi[2].x, bi[2].y, s, lutp);
  w1.y = dq2(bi[2].z, bi[2].w, s, lutp);
  w1.z = dq2(bi[3].x, bi[3].y, s, lutp);
  w1.w = dq2(bi[3].z, bi[3].w, s, lutp);
  *reinterpret_cast<uint4*>(lb + (pb ^ 1) * BSTRIDE) = w0;
  *reinterpret_cast<uint4*>(lb + (pb ^ 1) * BSTRIDE + 8) = w1;
  __builtin_amdgcn_sched_barrier(0);
  // refill: idx(kt+3) (clamped at tail to keep issue counts uniform)
  {
    const int ksc = (kt + 3 < NT) ? kt + 3 : NT - 1;
    const int4* gbk = (const int4*)(gb0 + (size_t)ksc * BK);
    bi[0] = gbk[0];
    bi[1] = gbk[1];
    bi[2] = gbk[2];
    bi[3] = gbk[3];
    s = gs[ksc];
  }
  asm volatile("s_waitcnt lgkmcnt(0)" ::: "memory");  // b[pb^1] writes flushed
  __builtin_amdgcn_s_barrier();                       // publish; vmcnt survives
}

// =============== main fused GEMM (split-K=2, atomic epilogue) ===============
// BM=256 x BN=64, BK=64, 4 waves; wave w owns rows [w*64, w*64+64), acc 4x4.
__launch_bounds__(256, 3)
__global__ void k_main(const ushort_t* __restrict__ xbf, const int* __restrict__ wi,
                       const float* __restrict__ sc, const ushort_t* __restrict__ xap,
                       const ushort_t* __restrict__ btp, float* __restrict__ out) {
  __shared__ __align__(16) ushort_t lds_a[BM * BK];     // 32 KB, swizzled
  __shared__ __align__(16) ushort_t lds_b[2][BSTRIDE];  // 2 x 9 KB, +8 pad
  __shared__ float2 lutp[256];                          // pair LUT, 2 KB

  const int t = threadIdx.x;
  const int lane = t & 63;
  const int w = t >> 6;

  // XCD-chunked bijective swizzle: 688 = 8 XCDs x 86; the 4 (mblk,kh)
  // siblings stay adjacent -> same XCD L2 serves the shared B-index panel.
  const int n = blockIdx.x;
  const int wg = (n & 7) * 86 + (n >> 3);
  const int o0 = (wg >> 2) * BN;
  const int kh = (wg >> 1) & 1;
  const int m0 = (wg & 1) * BM;
  const int k0 = kh * KHALF;

  lutp[t] = make_float2(c_nf4[t & 15], c_nf4[t >> 4]);
  __syncthreads();  // lutp visible before prologue dequant

  // B staging: thread -> (row=t>>2, 16 ints at (t&3)*16)
  const int brow = t >> 2, bq = t & 3;
  const int* gb0 = wi + (size_t)(o0 + brow) * K_DIM + k0 + bq * 16;
  const float* gs = sc + (size_t)(o0 + brow) * 64 + kh * 32;  // 1 scale/row/tile
  ushort_t* lb = &lds_b[0][brow * 72 + bq * 16];

  // A DMA: wave w stages its own rows [w*64, w*64+64); 8 instrs x 1KB
  const ushort_t* ga =
      xbf + (size_t)(m0 + w * 64 + (lane >> 3)) * K_DIM + k0 + (lane & 7) * 8;
  ushort_t* la_dst = lds_a + w * 4096 + lane * 8;

  f32x4 acc[4][4];
#pragma unroll
  for (int mi = 0; mi < 4; ++mi)
#pragma unroll
    for (int ni = 0; ni < 4; ++ni) acc[mi][ni] = (f32x4){0.f, 0.f, 0.f, 0.f};

  // prologue: dequant tile 0 straight into b[0], then FIFO-pinned issue of
  // [ idx(1) x5, DMA_A(0) x8, idx(2) x5 ] to establish the loop invariant.
  {
    const int4* g0 = (const int4*)gb0;
    int4 c0 = g0[0], c1 = g0[1], c2 = g0[2], c3 = g0[3];
    float s0 = gs[0];
    uint4 w0, w1;
    w0.x = dq2(c0.x, c0.y, s0, lutp);
    w0.y = dq2(c0.z, c0.w, s0, lutp);
    w0.z = dq2(c1.x, c1.y, s0, lutp);
    w0.w = dq2(c1.z, c1.w, s0, lutp);
    w1.x = dq2(c2.x, c2.y, s0, lutp);
    w1.y = dq2(c2.z, c2.w, s0, lutp);
    w1.z = dq2(c3.x, c3.y, s0, lutp);
    w1.w = dq2(c3.z, c3.w, s0, lutp);
    *reinterpret_cast<uint4*>(lb) = w0;
    *reinterpret_cast<uint4*>(lb + 8) = w1;
  }
  __builtin_amdgcn_sched_barrier(0);
  int4 biA[4], biB[4];
  float sA, sB;
  {
    const int4* g1 = (const int4*)(gb0 + BK);
    biA[0] = g1[0];
    biA[1] = g1[1];
    biA[2] = g1[2];
    biA[3] = g1[3];
    sA = gs[1];
  }
  __builtin_amdgcn_sched_barrier(0);
#pragma unroll
  for (int j = 0; j < 8; ++j) async16(ga + (size_t)j * 8 * K_DIM, la_dst + j * 512);
  __builtin_amdgcn_sched_barrier(0);
  {
    const int4* g2 = (const int4*)(gb0 + 2 * BK);
    biB[0] = g2[0];
    biB[1] = g2[1];
    biB[2] = g2[2];
    biB[3] = g2[3];
    sB = gs[2];
  }
  __builtin_amdgcn_sched_barrier(0);
  asm volatile("s_waitcnt lgkmcnt(0)" ::: "memory");  // b[0] writes flushed
  __builtin_amdgcn_s_barrier();                       // publish b[0]; loads fly on

  const ushort_t* afb = lds_a + (w * 64 + (lane & 15)) * BK;
  const int q = lane >> 4;
  const ushort_t* bfb = &lds_b[0][(lane & 15) * 72 + q * 8];

#pragma unroll 1
  for (int kt2 = 0; kt2 < NT / 2; ++kt2) {
    tile_step(2 * kt2, biA, sA, lutp, lb, bfb, afb, ga, la_dst, gb0, gs, lane, q, acc);
    tile_step(2 * kt2 + 1, biB, sB, lutp, lb, bfb, afb, ga, la_dst, gb0, gs, lane, q, acc);
  }

  // drain trailing clamped prefetches (garbage DMA/idx) before tail/exit
  asm volatile("s_waitcnt vmcnt(0)" ::: "memory");

  // LoRA K-extension tail (kh==1 only): BK=32, A from xap, B from btp
  if (kh == 1) {
    uint4 braw = *reinterpret_cast<const uint4*>(btp + (size_t)(o0 + brow) * 32 + bq * 8);
    __syncthreads();
    *reinterpret_cast<uint4*>(&lds_b[0][brow * 72 + bq * 8]) = braw;
#pragma unroll
    for (int j = 0; j < 4; ++j)
      async16(xap + (size_t)(m0 + w * 64 + j * 16 + (lane >> 2)) * 32 + (lane & 3) * 8,
              lds_a + w * 2048 + j * 512 + lane * 8);
    __syncthreads();
    bf16x8 av[4], bv[4];
#pragma unroll
    for (int mi = 0; mi < 4; ++mi)
      av[mi] = ldfrag(lds_a + w * 2048 + (mi * 16 + (lane & 15)) * 32 + q * 8);
#pragma unroll
    for (int ni = 0; ni < 4; ++ni)
      bv[ni] = ldfrag(&lds_b[0][(ni * 16 + (lane & 15)) * 72 + q * 8]);
#pragma unroll
    for (int mi = 0; mi < 4; ++mi)
#pragma unroll
      for (int ni = 0; ni < 4; ++ni)
        acc[mi][ni] = __builtin_amdgcn_mfma_f32_16x16x32_bf16(av[mi], bv[ni],
                                                              acc[mi][ni], 0, 0, 0);
  }

  // epilogue: atomic add onto bias-pre-initialized out
  const int cl = lane & 15, rg = (lane >> 4) * 4;
#pragma unroll
  for (int ni = 0; ni < 4; ++ni) {
    int col = o0 + ni * 16 + cl;
#pragma unroll
    for (int mi = 0; mi < 4; ++mi) {
      int row0 = m0 + w * 64 + mi * 16 + rg;
      float* op = out + (size_t)row0 * N_OUT + col;
#pragma unroll
      for (int i = 0; i < 4; ++i) atomicAdd(op + (size_t)i * N_OUT, acc[mi][ni][i]);
    }
  }
}

extern "C" void kernel_launch(void* const* d_in, const int* in_sizes, int n_in,
                              void* d_out, int out_size, void* d_ws, size_t ws_size,
                              hipStream_t stream) {
  const float* x = (const float*)d_in[0];
  const int* wi = (const int*)d_in[1];
  const float* sc = (const float*)d_in[2];
  const float* lA = (const float*)d_in[3];
  const float* lB = (const float*)d_in[4];
  const float* bias = (const float*)d_in[5];
  float* out = (float*)d_out;

  char* wsb = (char*)d_ws;
  ushort_t* xbf = (ushort_t*)wsb;                               // 4 MB
  ushort_t* xap = (ushort_t*)(wsb + (4u << 20));                // 32 KB
  ushort_t* btp = (ushort_t*)(wsb + (4u << 20) + (32u << 10));  // 704 KB

  k_prep<<<7083, 256, 0, stream>>>(x, lA, lB, bias, xbf, xap, btp, out);
  k_main<<<688, 256, 0, stream>>>(xbf, wi, sc, xap, btp, out);
}

// Round 4
// 380.393 us; speedup vs baseline: 1.0127x; 1.0127x over previous
//
#include <hip/hip_runtime.h>
#include <stdint.h>

typedef __bf16 bf16x8 __attribute__((ext_vector_type(8)));
typedef float f32x4 __attribute__((ext_vector_type(4)));
typedef unsigned short ushort_t;

#define N_OUT 11008
#define K_DIM 4096
#define M_DIM 512
#define BM 256
#define BN 64
#define BK 64
#define KHALF 1024 /* split-K = 4 */
#define NT 16      /* KHALF / BK */

__constant__ float c_nf4[16] = {
    -1.0f, -0.6961928009986877f, -0.5250730514526367f, -0.39491748809814453f,
    -0.28444138169288635f, -0.18477343022823334f, -0.09105003625154495f, 0.0f,
    0.07958029955625534f, 0.16093020141124725f, 0.24611230194568634f,
    0.33791524171829224f, 0.44070982933044434f, 0.5626170039176941f,
    0.7229568362236023f, 1.0f};

// round-half-up fp32 -> bf16, pack two into u32
__device__ __forceinline__ uint32_t pkbf(float lo, float hi) {
  uint32_t ul = __builtin_bit_cast(uint32_t, lo);
  uint32_t uh = __builtin_bit_cast(uint32_t, hi);
  return ((ul + 0x8000u) >> 16) | ((uh + 0x8000u) & 0xffff0000u);
}

__device__ __forceinline__ void async16(const void* g, void* l) {
  __builtin_amdgcn_global_load_lds(
      (const __attribute__((address_space(1))) void*)g,
      (__attribute__((address_space(3))) void*)l, 16, 0, 0);
}

__device__ __forceinline__ bf16x8 ldfrag(const ushort_t* p) {
  uint4 r = *reinterpret_cast<const uint4*>(p);
  return __builtin_bit_cast(bf16x8, r);
}

__device__ __forceinline__ uint32_t dq2(int a, int b, float s, const float2* lut) {
  float2 l = lut[a | (b << 4)];
  return pkbf(l.x * s, l.y * s);
}

// =============== fused prep: cvt+swizzle | x@A | B^T | bias-init =============
// grid: [0,1024) cvt, [1024,1536) xa, [1536,1579) bt, [1579,7083) bias-init
__global__ void k_prep(const float* __restrict__ x, const float* __restrict__ lA,
                       const float* __restrict__ lB, const float* __restrict__ bias,
                       ushort_t* __restrict__ xbf, ushort_t* __restrict__ xap,
                       ushort_t* __restrict__ btp, float* __restrict__ out) {
  const int b = blockIdx.x, t = threadIdx.x;
  if (b < 1024) {
    // x fp32 -> bf16 with XOR chunk swizzle inside each 64-elem k-window:
    // stored chunk position cp holds original chunk cp ^ (m&7)
    int oc = b * 256 + t;          // 16B output chunk id (8 bf16)
    int m = oc >> 9;               // 512 chunks per row
    int cr = oc & 511;
    int win = cr >> 3, cp = cr & 7;
    int c = cp ^ (m & 7);
    const float4* s4 = (const float4*)(x + (size_t)m * K_DIM + win * 64 + c * 8);
    float4 v0 = s4[0], v1 = s4[1];
    uint4 o;
    o.x = pkbf(v0.x, v0.y);
    o.y = pkbf(v0.z, v0.w);
    o.z = pkbf(v1.x, v1.y);
    o.w = pkbf(v1.z, v1.w);
    ((uint4*)xbf)[oc] = o;
  } else if (b < 1536) {
    // xa = 2*(x @ lora_A) for one row m, padded [512,32] bf16
    __shared__ float red[256 * 17];
    int m = b - 1024;
    int ks = t * 16;
    alignas(16) float xs[16];
    const f32x4* xv = (const f32x4*)(x + (size_t)m * K_DIM + ks);
    ((f32x4*)xs)[0] = xv[0];
    ((f32x4*)xs)[1] = xv[1];
    ((f32x4*)xs)[2] = xv[2];
    ((f32x4*)xs)[3] = xv[3];
    f32x4 ac0 = 0.f, ac1 = 0.f, ac2 = 0.f, ac3 = 0.f;
#pragma unroll
    for (int kk = 0; kk < 16; ++kk) {
      float xk = xs[kk];
      const f32x4* l4 = (const f32x4*)(lA + (size_t)(ks + kk) * 16);
      ac0 += xk * l4[0];
      ac1 += xk * l4[1];
      ac2 += xk * l4[2];
      ac3 += xk * l4[3];
    }
#pragma unroll
    for (int r = 0; r < 4; ++r) {
      red[t * 17 + r] = ac0[r];
      red[t * 17 + 4 + r] = ac1[r];
      red[t * 17 + 8 + r] = ac2[r];
      red[t * 17 + 12 + r] = ac3[r];
    }
    __syncthreads();
#pragma unroll
    for (int s = 128; s >= 16; s >>= 1) {
      if (t < s)
        for (int r = 0; r < 16; ++r) red[t * 17 + r] += red[(t + s) * 17 + r];
      __syncthreads();
    }
    if (t < 32) {
      float v = 0.f;
      if (t < 16) {
        for (int p = 0; p < 16; ++p) v += red[p * 17 + t];
        v *= 2.0f;  // SCALING
      }
      uint32_t u = __builtin_bit_cast(uint32_t, v);
      xap[(size_t)m * 32 + t] = (ushort_t)((u + 0x8000u) >> 16);
    }
  } else if (b < 1579) {
    // Bt = lora_B^T, padded [11008,32] bf16
    int o = (b - 1536) * 256 + t;
    uint32_t p[8];
#pragma unroll
    for (int j = 0; j < 8; ++j)
      p[j] = pkbf(lB[(size_t)(2 * j) * N_OUT + o], lB[(size_t)(2 * j + 1) * N_OUT + o]);
    uint4* dst = reinterpret_cast<uint4*>(btp + (size_t)o * 32);
    dst[0] = make_uint4(p[0], p[1], p[2], p[3]);
    dst[1] = make_uint4(p[4], p[5], p[6], p[7]);
    dst[2] = make_uint4(0u, 0u, 0u, 0u);
    dst[3] = make_uint4(0u, 0u, 0u, 0u);
  } else {
    // out = broadcast bias (split-K blocks atomically add on top)
    int i = (b - 1579) * 256 + t;  // float4 id, 1,409,024 total
    int col4 = i % 2752;           // 11008/4
    ((float4*)out)[i] = ((const float4*)bias)[col4];
  }
}

// =============== main fused GEMM (split-K=4, atomic epilogue) ===============
// ROUND-0 STRUCTURE RESTORED (two __syncthreads per tile, compiler-scheduled)
// with three orthogonal deltas: split-K=4 (more resident blocks -> TLP hides
// latency), XCD-chunked block swizzle (proven -36% FETCH), and A-DMA issued
// BEFORE the dequant (dequant VALU covers part of the DMA L2 latency before
// the drain barrier).
// BM=256 x BN=64, BK=64, 4 waves; wave w owns rows [w*64, w*64+64), acc 4x4.
__launch_bounds__(256, 3)
__global__ void k_main(const ushort_t* __restrict__ xbf, const int* __restrict__ wi,
                       const float* __restrict__ sc, const ushort_t* __restrict__ xap,
                       const ushort_t* __restrict__ btp, float* __restrict__ out) {
  __shared__ __align__(16) ushort_t lds_a[BM * BK];  // 32 KB, [row][c'], swizzled
  __shared__ __align__(16) ushort_t lds_b[BN * 72];  // 9 KB, +8 pad
  __shared__ float2 lutp[256];                       // pair LUT, 2 KB

  const int t = threadIdx.x;
  const int lane = t & 63;
  const int w = t >> 6;

  // XCD-chunked bijective swizzle: 1376 blocks = 8 XCDs x 172. The 8
  // (kh,m0) siblings of one o0 stay adjacent; the m-pairs sharing a wi
  // panel land on the same XCD L2.
  const int n = blockIdx.x;
  const int wg = (n & 7) * 172 + (n >> 3);
  const int sib = wg & 7;
  const int o0 = (wg >> 3) * BN;
  const int kh = sib >> 1;            // 0..3
  const int m0 = (sib & 1) * BM;      // 0 or 256
  const int k0 = kh * KHALF;

  lutp[t] = make_float2(c_nf4[t & 15], c_nf4[t >> 4]);

  // B staging: thread -> (row=t>>2, 16 ints at (t&3)*16)
  const int brow = t >> 2, bq = t & 3;
  const int* gb = wi + (size_t)(o0 + brow) * K_DIM + k0 + bq * 16;
  const float* gs = sc + (size_t)(o0 + brow) * 64 + kh * 16;  // 1 scale/row/tile
  ushort_t* lb = lds_b + brow * 72 + bq * 16;

  // A DMA: wave w stages its own rows [w*64, w*64+64); 8 instrs x 1KB
  const ushort_t* ga =
      xbf + (size_t)(m0 + w * 64 + (lane >> 3)) * K_DIM + k0 + (lane & 7) * 8;
  ushort_t* la_dst = lds_a + w * 4096 + lane * 8;

  f32x4 acc[4][4];
#pragma unroll
  for (int mi = 0; mi < 4; ++mi)
#pragma unroll
    for (int ni = 0; ni < 4; ++ni) acc[mi][ni] = (f32x4){0.f, 0.f, 0.f, 0.f};

  // prologue: prefetch tile 0 indices + scale
  int4 bi0 = ((const int4*)gb)[0], bi1 = ((const int4*)gb)[1];
  int4 bi2 = ((const int4*)gb)[2], bi3 = ((const int4*)gb)[3];
  float s = gs[0];
  gb += BK;
  uint4 braw;

  const ushort_t* afb = lds_a + (w * 64 + (lane & 15)) * BK;
  const int q = lane >> 4;
  const ushort_t* bfb = lds_b + (lane & 15) * 72 + q * 8;

#pragma unroll 1
  for (int kt = 0; kt < NT; ++kt) {
    __syncthreads();  // prev tile's frag reads done (covers LUT init at kt=0)
    // A DMA first: dequant VALU below covers part of its L2 latency
#pragma unroll
    for (int j = 0; j < 8; ++j)
      async16(ga + (size_t)j * 8 * K_DIM + kt * BK, la_dst + j * 512);
    // dequant 16 idx -> 16 bf16 via pair LUT, 2x ds_write_b128
    uint4 w0, w1;
    w0.x = dq2(bi0.x, bi0.y, s, lutp);
    w0.y = dq2(bi0.z, bi0.w, s, lutp);
    w0.z = dq2(bi1.x, bi1.y, s, lutp);
    w0.w = dq2(bi1.z, bi1.w, s, lutp);
    w1.x = dq2(bi2.x, bi2.y, s, lutp);
    w1.y = dq2(bi2.z, bi2.w, s, lutp);
    w1.z = dq2(bi3.x, bi3.y, s, lutp);
    w1.w = dq2(bi3.z, bi3.w, s, lutp);
    *reinterpret_cast<uint4*>(lb) = w0;
    *reinterpret_cast<uint4*>(lb + 8) = w1;
    __syncthreads();  // drains DMA + makes lds_b visible
    // prefetch next tile (in flight during MFMA phase)
    if (kt + 1 < NT) {
      bi0 = ((const int4*)gb)[0];
      bi1 = ((const int4*)gb)[1];
      bi2 = ((const int4*)gb)[2];
      bi3 = ((const int4*)gb)[3];
      s = gs[kt + 1];
      gb += BK;
    } else if (kh == 3) {
      braw = *reinterpret_cast<const uint4*>(btp + (size_t)(o0 + brow) * 32 + bq * 8);
    }
    // fragments + 32 MFMA
#pragma unroll
    for (int kc = 0; kc < 2; ++kc) {
      const int cpr = ((kc * 4 + q) ^ (lane & 7)) * 8;  // un-swizzle
      bf16x8 av[4], bv[4];
#pragma unroll
      for (int mi = 0; mi < 4; ++mi) av[mi] = ldfrag(afb + mi * 16 * BK + cpr);
#pragma unroll
      for (int ni = 0; ni < 4; ++ni) bv[ni] = ldfrag(bfb + ni * 16 * 72 + kc * 32);
#pragma unroll
      for (int mi = 0; mi < 4; ++mi)
#pragma unroll
        for (int ni = 0; ni < 4; ++ni)
          acc[mi][ni] = __builtin_amdgcn_mfma_f32_16x16x32_bf16(av[mi], bv[ni],
                                                                acc[mi][ni], 0, 0, 0);
    }
  }

  // LoRA K-extension tail (kh==3 only): BK=32, A from xap, B from btp
  if (kh == 3) {
    __syncthreads();
    *reinterpret_cast<uint4*>(lds_b + brow * 72 + bq * 8) = braw;
#pragma unroll
    for (int j = 0; j < 4; ++j)
      async16(xap + (size_t)(m0 + w * 64 + j * 16 + (lane >> 2)) * 32 + (lane & 3) * 8,
              lds_a + w * 2048 + j * 512 + lane * 8);
    __syncthreads();
    bf16x8 av[4], bv[4];
#pragma unroll
    for (int mi = 0; mi < 4; ++mi)
      av[mi] = ldfrag(lds_a + w * 2048 + (mi * 16 + (lane & 15)) * 32 + q * 8);
#pragma unroll
    for (int ni = 0; ni < 4; ++ni)
      bv[ni] = ldfrag(lds_b + (ni * 16 + (lane & 15)) * 72 + q * 8);
#pragma unroll
    for (int mi = 0; mi < 4; ++mi)
#pragma unroll
      for (int ni = 0; ni < 4; ++ni)
        acc[mi][ni] = __builtin_amdgcn_mfma_f32_16x16x32_bf16(av[mi], bv[ni],
                                                              acc[mi][ni], 0, 0, 0);
  }

  // epilogue: atomic add onto bias-pre-initialized out
  const int cl = lane & 15, rg = q * 4;
#pragma unroll
  for (int ni = 0; ni < 4; ++ni) {
    int col = o0 + ni * 16 + cl;
#pragma unroll
    for (int mi = 0; mi < 4; ++mi) {
      int row0 = m0 + w * 64 + mi * 16 + rg;
      float* op = out + (size_t)row0 * N_OUT + col;
#pragma unroll
      for (int i = 0; i < 4; ++i) atomicAdd(op + (size_t)i * N_OUT, acc[mi][ni][i]);
    }
  }
}

extern "C" void kernel_launch(void* const* d_in, const int* in_sizes, int n_in,
                              void* d_out, int out_size, void* d_ws, size_t ws_size,
                              hipStream_t stream) {
  const float* x = (const float*)d_in[0];
  const int* wi = (const int*)d_in[1];
  const float* sc = (const float*)d_in[2];
  const float* lA = (const float*)d_in[3];
  const float* lB = (const float*)d_in[4];
  const float* bias = (const float*)d_in[5];
  float* out = (float*)d_out;

  char* wsb = (char*)d_ws;
  ushort_t* xbf = (ushort_t*)wsb;                               // 4 MB
  ushort_t* xap = (ushort_t*)(wsb + (4u << 20));                // 32 KB
  ushort_t* btp = (ushort_t*)(wsb + (4u << 20) + (32u << 10));  // 704 KB

  k_prep<<<7083, 256, 0, stream>>>(x, lA, lB, bias, xbf, xap, btp, out);
  k_main<<<1376, 256, 0, stream>>>(xbf, wi, sc, xap, btp, out);
}

// Round 5
// 369.815 us; speedup vs baseline: 1.0417x; 1.0286x over previous
//
#include <hip/hip_runtime.h>
#include <stdint.h>

typedef __bf16 bf16x8 __attribute__((ext_vector_type(8)));
typedef float f32x4 __attribute__((ext_vector_type(4)));
typedef unsigned short ushort_t;

#define N_OUT 11008
#define K_DIM 4096
#define M_DIM 512
#define BM 256
#define BN 64
#define BK 64
#define KHALF 2048
#define NT 32 /* KHALF / BK */
#define BSTRIDE (BN * 72)

// compiler-only memory fence: emits NO instruction, blocks memory-op
// reordering only (unlike sched_barrier(0), which pins ALL scheduling
// and caused the m141-style regressions in rounds 1-3).
#define FENCE() asm volatile("" ::: "memory")

__constant__ float c_nf4[16] = {
    -1.0f, -0.6961928009986877f, -0.5250730514526367f, -0.39491748809814453f,
    -0.28444138169288635f, -0.18477343022823334f, -0.09105003625154495f, 0.0f,
    0.07958029955625534f, 0.16093020141124725f, 0.24611230194568634f,
    0.33791524171829224f, 0.44070982933044434f, 0.5626170039176941f,
    0.7229568362236023f, 1.0f};

// round-half-up fp32 -> bf16, pack two into u32
__device__ __forceinline__ uint32_t pkbf(float lo, float hi) {
  uint32_t ul = __builtin_bit_cast(uint32_t, lo);
  uint32_t uh = __builtin_bit_cast(uint32_t, hi);
  return ((ul + 0x8000u) >> 16) | ((uh + 0x8000u) & 0xffff0000u);
}

__device__ __forceinline__ void async16(const void* g, void* l) {
  __builtin_amdgcn_global_load_lds(
      (const __attribute__((address_space(1))) void*)g,
      (__attribute__((address_space(3))) void*)l, 16, 0, 0);
}

__device__ __forceinline__ bf16x8 ldfrag(const ushort_t* p) {
  uint4 r = *reinterpret_cast<const uint4*>(p);
  return __builtin_bit_cast(bf16x8, r);
}

__device__ __forceinline__ uint32_t dq2(int a, int b, float s, const float2* lut) {
  float2 l = lut[a | (b << 4)];
  return pkbf(l.x * s, l.y * s);
}

// =============== fused prep: cvt+swizzle | x@A | B^T | bias-init =============
// grid: [0,1024) cvt, [1024,1536) xa, [1536,1579) bt, [1579,7083) bias-init
__global__ void k_prep(const float* __restrict__ x, const float* __restrict__ lA,
                       const float* __restrict__ lB, const float* __restrict__ bias,
                       ushort_t* __restrict__ xbf, ushort_t* __restrict__ xap,
                       ushort_t* __restrict__ btp, float* __restrict__ out) {
  const int b = blockIdx.x, t = threadIdx.x;
  if (b < 1024) {
    // x fp32 -> bf16 with XOR chunk swizzle inside each 64-elem k-window:
    // stored chunk position cp holds original chunk cp ^ (m&7)
    int oc = b * 256 + t;          // 16B output chunk id (8 bf16)
    int m = oc >> 9;               // 512 chunks per row
    int cr = oc & 511;
    int win = cr >> 3, cp = cr & 7;
    int c = cp ^ (m & 7);
    const float4* s4 = (const float4*)(x + (size_t)m * K_DIM + win * 64 + c * 8);
    float4 v0 = s4[0], v1 = s4[1];
    uint4 o;
    o.x = pkbf(v0.x, v0.y);
    o.y = pkbf(v0.z, v0.w);
    o.z = pkbf(v1.x, v1.y);
    o.w = pkbf(v1.z, v1.w);
    ((uint4*)xbf)[oc] = o;
  } else if (b < 1536) {
    // xa = 2*(x @ lora_A) for one row m, padded [512,32] bf16
    __shared__ float red[256 * 17];
    int m = b - 1024;
    int ks = t * 16;
    alignas(16) float xs[16];
    const f32x4* xv = (const f32x4*)(x + (size_t)m * K_DIM + ks);
    ((f32x4*)xs)[0] = xv[0];
    ((f32x4*)xs)[1] = xv[1];
    ((f32x4*)xs)[2] = xv[2];
    ((f32x4*)xs)[3] = xv[3];
    f32x4 ac0 = 0.f, ac1 = 0.f, ac2 = 0.f, ac3 = 0.f;
#pragma unroll
    for (int kk = 0; kk < 16; ++kk) {
      float xk = xs[kk];
      const f32x4* l4 = (const f32x4*)(lA + (size_t)(ks + kk) * 16);
      ac0 += xk * l4[0];
      ac1 += xk * l4[1];
      ac2 += xk * l4[2];
      ac3 += xk * l4[3];
    }
#pragma unroll
    for (int r = 0; r < 4; ++r) {
      red[t * 17 + r] = ac0[r];
      red[t * 17 + 4 + r] = ac1[r];
      red[t * 17 + 8 + r] = ac2[r];
      red[t * 17 + 12 + r] = ac3[r];
    }
    __syncthreads();
#pragma unroll
    for (int s = 128; s >= 16; s >>= 1) {
      if (t < s)
        for (int r = 0; r < 16; ++r) red[t * 17 + r] += red[(t + s) * 17 + r];
      __syncthreads();
    }
    if (t < 32) {
      float v = 0.f;
      if (t < 16) {
        for (int p = 0; p < 16; ++p) v += red[p * 17 + t];
        v *= 2.0f;  // SCALING
      }
      uint32_t u = __builtin_bit_cast(uint32_t, v);
      xap[(size_t)m * 32 + t] = (ushort_t)((u + 0x8000u) >> 16);
    }
  } else if (b < 1579) {
    // Bt = lora_B^T, padded [11008,32] bf16
    int o = (b - 1536) * 256 + t;
    uint32_t p[8];
#pragma unroll
    for (int j = 0; j < 8; ++j)
      p[j] = pkbf(lB[(size_t)(2 * j) * N_OUT + o], lB[(size_t)(2 * j + 1) * N_OUT + o]);
    uint4* dst = reinterpret_cast<uint4*>(btp + (size_t)o * 32);
    dst[0] = make_uint4(p[0], p[1], p[2], p[3]);
    dst[1] = make_uint4(p[4], p[5], p[6], p[7]);
    dst[2] = make_uint4(0u, 0u, 0u, 0u);
    dst[3] = make_uint4(0u, 0u, 0u, 0u);
  } else {
    // out = broadcast bias (split-K blocks atomically add on top)
    int i = (b - 1579) * 256 + t;  // float4 id, 1,409,024 total
    int col4 = i % 2752;           // 11008/4
    ((float4*)out)[i] = ((const float4*)bias)[col4];
  }
}

// =============== main fused GEMM (split-K=2, atomic epilogue) ===============
// R2's pipeline architecture with the scheduling poison removed:
//   - 2-deep idx prefetch (biA/biB), window > HBM latency
//   - one raw s_barrier per tile, counted vmcnt(5), NO vmcnt(0) in loop
//   - FIFO order (DMA before idx) enforced by FREE compiler fences only
//     (no sched_barrier(0) -> compiler keeps its fine-grained lgkmcnt
//      interleave of ds_read/MFMA)
// Steady state entering tile kt: outstanding = [DMA_A(kt)x8, idx(kt+1)x5],
// bi regs hold idx(kt). Compiler auto-waits vmcnt(13) at dequant (free);
// explicit vmcnt(5) after the barrier drains exactly DMA_A(kt).
// Per tile: dequant -> lgkm0 -> barrier -> vmcnt(5) -> kc0 reads+MFMA ->
// kc1 reads -> lgkm0 (lds_a reusable) -> DMA(kt+1) -> fence -> idx(kt+2)
// -> kc1 MFMA. lds_a stays single-buffered (wave-private rows).
__launch_bounds__(256, 3)
__global__ void k_main(const ushort_t* __restrict__ xbf, const int* __restrict__ wi,
                       const float* __restrict__ sc, const ushort_t* __restrict__ xap,
                       const ushort_t* __restrict__ btp, float* __restrict__ out) {
  __shared__ __align__(16) ushort_t lds_a[BM * BK];     // 32 KB, swizzled
  __shared__ __align__(16) ushort_t lds_b[2][BSTRIDE];  // 18 KB, +8 pad, dbuf
  __shared__ float2 lutp[256];                          // pair LUT, 2 KB

  const int t = threadIdx.x;
  const int lane = t & 63;
  const int w = t >> 6;

  // R0's plain grid mapping (no XCD swizzle): kh in grid.z keeps the two
  // atomic writers of each out tile far apart in dispatch order.
  const int o0 = blockIdx.x * BN;
  const int m0 = blockIdx.y * BM;
  const int kh = blockIdx.z;
  const int k0 = kh * KHALF;

  lutp[t] = make_float2(c_nf4[t & 15], c_nf4[t >> 4]);

  // B staging: thread -> (row=t>>2, 16 ints at (t&3)*16)
  const int brow = t >> 2, bq = t & 3;
  const int* gb0 = wi + (size_t)(o0 + brow) * K_DIM + k0 + bq * 16;
  const float* gs = sc + (size_t)(o0 + brow) * 64 + kh * 32;  // 1 scale/row/tile
  ushort_t* lb = &lds_b[0][brow * 72 + bq * 16];

  // A DMA: wave w stages its own rows [w*64, w*64+64); 8 instrs x 1KB
  const ushort_t* ga =
      xbf + (size_t)(m0 + w * 64 + (lane >> 3)) * K_DIM + k0 + (lane & 7) * 8;
  ushort_t* la_dst = lds_a + w * 4096 + lane * 8;

  f32x4 acc[4][4];
#pragma unroll
  for (int mi = 0; mi < 4; ++mi)
#pragma unroll
    for (int ni = 0; ni < 4; ++ni) acc[mi][ni] = (f32x4){0.f, 0.f, 0.f, 0.f};

  __syncthreads();  // lutp visible; nothing in flight yet

  // prologue, FIFO via free fences: idx(0)x5, DMA_A(0)x8, idx(1)x5
  int4 biA[4], biB[4];
  float sA, sB;
  {
    const int4* g0 = (const int4*)gb0;
    biA[0] = g0[0];
    biA[1] = g0[1];
    biA[2] = g0[2];
    biA[3] = g0[3];
    sA = gs[0];
  }
  FENCE();
#pragma unroll
  for (int j = 0; j < 8; ++j) async16(ga + (size_t)j * 8 * K_DIM, la_dst + j * 512);
  FENCE();
  {
    const int4* g1 = (const int4*)(gb0 + BK);
    biB[0] = g1[0];
    biB[1] = g1[1];
    biB[2] = g1[2];
    biB[3] = g1[3];
    sB = gs[1];
  }
  FENCE();

  const ushort_t* afb = lds_a + (w * 64 + (lane & 15)) * BK;
  const int q = lane >> 4;
  const ushort_t* bfb = &lds_b[0][(lane & 15) * 72 + q * 8];

// one half-tile: dequant BI into b[PB], barrier, vmcnt(5), 2x(frags+MFMA);
// mid-phase: DMA(kt+1) then refill BI with idx(kt+2) (clamped at tail).
#define HALF_TILE(KT, PB, BI, SS)                                              \
  {                                                                            \
    const int kt_ = (KT);                                                      \
    uint4 w0, w1;                                                              \
    w0.x = dq2(BI[0].x, BI[0].y, SS, lutp);                                    \
    w0.y = dq2(BI[0].z, BI[0].w, SS, lutp);                                    \
    w0.z = dq2(BI[1].x, BI[1].y, SS, lutp);                                    \
    w0.w = dq2(BI[1].z, BI[1].w, SS, lutp);                                    \
    w1.x = dq2(BI[2].x, BI[2].y, SS, lutp);                                    \
    w1.y = dq2(BI[2].z, BI[2].w, SS, lutp);                                    \
    w1.z = dq2(BI[3].x, BI[3].y, SS, lutp);                                    \
    w1.w = dq2(BI[3].z, BI[3].w, SS, lutp);                                    \
    *reinterpret_cast<uint4*>(lb + (PB)*BSTRIDE) = w0;                         \
    *reinterpret_cast<uint4*>(lb + (PB)*BSTRIDE + 8) = w1;                     \
    asm volatile("s_waitcnt lgkmcnt(0)" ::: "memory"); /* writes flushed */    \
    __builtin_amdgcn_s_barrier();                      /* vmcnt survives */    \
    asm volatile("s_waitcnt vmcnt(5)" ::: "memory");   /* DMA(kt) landed */    \
    const ushort_t* bfbk = bfb + (PB)*BSTRIDE;                                 \
    bf16x8 av0[4], bv0[4], av1[4], bv1[4];                                     \
    {                                                                          \
      const int cpr = (q ^ (lane & 7)) * 8;                                    \
      for (int mi = 0; mi < 4; ++mi) av0[mi] = ldfrag(afb + mi * 16 * BK + cpr); \
      for (int ni = 0; ni < 4; ++ni) bv0[ni] = ldfrag(bfbk + ni * 16 * 72);    \
    }                                                                          \
    for (int mi = 0; mi < 4; ++mi)                                             \
      for (int ni = 0; ni < 4; ++ni)                                           \
        acc[mi][ni] = __builtin_amdgcn_mfma_f32_16x16x32_bf16(av0[mi], bv0[ni], \
                                                              acc[mi][ni], 0, 0, 0); \
    {                                                                          \
      const int cpr = ((4 + q) ^ (lane & 7)) * 8;                              \
      for (int mi = 0; mi < 4; ++mi) av1[mi] = ldfrag(afb + mi * 16 * BK + cpr); \
      for (int ni = 0; ni < 4; ++ni) bv1[ni] = ldfrag(bfbk + ni * 16 * 72 + 32); \
    }                                                                          \
    asm volatile("s_waitcnt lgkmcnt(0)" ::: "memory"); /* lds_a reusable */    \
    {                                                                          \
      const int ktn = (kt_ + 1 < NT) ? kt_ + 1 : NT - 1; /* clamped re-DMA */  \
      for (int j = 0; j < 8; ++j)                                              \
        async16(ga + (size_t)j * 8 * K_DIM + (size_t)ktn * BK, la_dst + j * 512); \
    }                                                                          \
    FENCE(); /* pin FIFO: DMA older than idx refill */                         \
    {                                                                          \
      const int ksc = (kt_ + 2 < NT) ? kt_ + 2 : NT - 1; /* clamped reload */  \
      const int4* gbk = (const int4*)(gb0 + (size_t)ksc * BK);                 \
      BI[0] = gbk[0];                                                          \
      BI[1] = gbk[1];                                                          \
      BI[2] = gbk[2];                                                          \
      BI[3] = gbk[3];                                                          \
      SS = gs[ksc];                                                            \
    }                                                                          \
    for (int mi = 0; mi < 4; ++mi)                                             \
      for (int ni = 0; ni < 4; ++ni)                                           \
        acc[mi][ni] = __builtin_amdgcn_mfma_f32_16x16x32_bf16(av1[mi], bv1[ni], \
                                                              acc[mi][ni], 0, 0, 0); \
  }

#pragma unroll 1
  for (int kt2 = 0; kt2 < NT / 2; ++kt2) {
    HALF_TILE(2 * kt2, 0, biA, sA)
    HALF_TILE(2 * kt2 + 1, 1, biB, sB)
  }
#undef HALF_TILE

  // drain trailing clamped prefetches before the tail reuses lds_a
  asm volatile("s_waitcnt vmcnt(0)" ::: "memory");

  // LoRA K-extension tail (kh==1 only): BK=32, A from xap, B from btp
  if (kh == 1) {
    uint4 braw = *reinterpret_cast<const uint4*>(btp + (size_t)(o0 + brow) * 32 + bq * 8);
    __syncthreads();
    *reinterpret_cast<uint4*>(&lds_b[0][brow * 72 + bq * 8]) = braw;
#pragma unroll
    for (int j = 0; j < 4; ++j)
      async16(xap + (size_t)(m0 + w * 64 + j * 16 + (lane >> 2)) * 32 + (lane & 3) * 8,
              lds_a + w * 2048 + j * 512 + lane * 8);
    __syncthreads();
    bf16x8 av[4], bv[4];
#pragma unroll
    for (int mi = 0; mi < 4; ++mi)
      av[mi] = ldfrag(lds_a + w * 2048 + (mi * 16 + (lane & 15)) * 32 + q * 8);
#pragma unroll
    for (int ni = 0; ni < 4; ++ni)
      bv[ni] = ldfrag(&lds_b[0][(ni * 16 + (lane & 15)) * 72 + q * 8]);
#pragma unroll
    for (int mi = 0; mi < 4; ++mi)
#pragma unroll
      for (int ni = 0; ni < 4; ++ni)
        acc[mi][ni] = __builtin_amdgcn_mfma_f32_16x16x32_bf16(av[mi], bv[ni],
                                                              acc[mi][ni], 0, 0, 0);
  }

  // epilogue: atomic add onto bias-pre-initialized out
  const int cl = lane & 15, rg = (lane >> 4) * 4;
#pragma unroll
  for (int ni = 0; ni < 4; ++ni) {
    int col = o0 + ni * 16 + cl;
#pragma unroll
    for (int mi = 0; mi < 4; ++mi) {
      int row0 = m0 + w * 64 + mi * 16 + rg;
      float* op = out + (size_t)row0 * N_OUT + col;
#pragma unroll
      for (int i = 0; i < 4; ++i) atomicAdd(op + (size_t)i * N_OUT, acc[mi][ni][i]);
    }
  }
}

extern "C" void kernel_launch(void* const* d_in, const int* in_sizes, int n_in,
                              void* d_out, int out_size, void* d_ws, size_t ws_size,
                              hipStream_t stream) {
  const float* x = (const float*)d_in[0];
  const int* wi = (const int*)d_in[1];
  const float* sc = (const float*)d_in[2];
  const float* lA = (const float*)d_in[3];
  const float* lB = (const float*)d_in[4];
  const float* bias = (const float*)d_in[5];
  float* out = (float*)d_out;

  char* wsb = (char*)d_ws;
  ushort_t* xbf = (ushort_t*)wsb;                               // 4 MB
  ushort_t* xap = (ushort_t*)(wsb + (4u << 20));                // 32 KB
  ushort_t* btp = (ushort_t*)(wsb + (4u << 20) + (32u << 10));  // 704 KB

  k_prep<<<7083, 256, 0, stream>>>(x, lA, lB, bias, xbf, xap, btp, out);
  dim3 grid(N_OUT / BN, M_DIM / BM, 2);
  k_main<<<grid, 256, 0, stream>>>(xbf, wi, sc, xap, btp, out);
}

// Round 6
// 347.279 us; speedup vs baseline: 1.1093x; 1.0649x over previous
//
#include <hip/hip_runtime.h>
#include <stdint.h>

typedef __bf16 bf16x8 __attribute__((ext_vector_type(8)));
typedef float f32x4 __attribute__((ext_vector_type(4)));
typedef unsigned short ushort_t;

#define N_OUT 11008
#define K_DIM 4096
#define M_DIM 512
#define BM 256
#define BN 64
#define BK 64
#define KHALF 2048
#define NT 32 /* KHALF / BK */

__constant__ float c_nf4[16] = {
    -1.0f, -0.6961928009986877f, -0.5250730514526367f, -0.39491748809814453f,
    -0.28444138169288635f, -0.18477343022823334f, -0.09105003625154495f, 0.0f,
    0.07958029955625534f, 0.16093020141124725f, 0.24611230194568634f,
    0.33791524171829224f, 0.44070982933044434f, 0.5626170039176941f,
    0.7229568362236023f, 1.0f};

// round-half-up fp32 -> bf16, pack two into u32
__device__ __forceinline__ uint32_t pkbf(float lo, float hi) {
  uint32_t ul = __builtin_bit_cast(uint32_t, lo);
  uint32_t uh = __builtin_bit_cast(uint32_t, hi);
  return ((ul + 0x8000u) >> 16) | ((uh + 0x8000u) & 0xffff0000u);
}

__device__ __forceinline__ void async16(const void* g, void* l) {
  __builtin_amdgcn_global_load_lds(
      (const __attribute__((address_space(1))) void*)g,
      (__attribute__((address_space(3))) void*)l, 16, 0, 0);
}

__device__ __forceinline__ bf16x8 ldfrag(const ushort_t* p) {
  uint4 r = *reinterpret_cast<const uint4*>(p);
  return __builtin_bit_cast(bf16x8, r);
}

__device__ __forceinline__ uint32_t dq2(int a, int b, float s, const float2* lut) {
  float2 l = lut[a | (b << 4)];
  return pkbf(l.x * s, l.y * s);
}

// =============== fused prep: cvt+swizzle | x@A | B^T =========================
// grid: [0,1024) cvt, [1024,1536) xa, [1536,1579) bt.  (bias-init branch is
// GONE: out is zeroed via hipMemsetAsync; bias folds into k_main's acc init.)
__global__ void k_prep(const float* __restrict__ x, const float* __restrict__ lA,
                       const float* __restrict__ lB,
                       ushort_t* __restrict__ xbf, ushort_t* __restrict__ xap,
                       ushort_t* __restrict__ btp) {
  const int b = blockIdx.x, t = threadIdx.x;
  if (b < 1024) {
    // x fp32 -> bf16 with XOR chunk swizzle inside each 64-elem k-window:
    // stored chunk position cp holds original chunk cp ^ (m&7)
    int oc = b * 256 + t;          // 16B output chunk id (8 bf16)
    int m = oc >> 9;               // 512 chunks per row
    int cr = oc & 511;
    int win = cr >> 3, cp = cr & 7;
    int c = cp ^ (m & 7);
    const float4* s4 = (const float4*)(x + (size_t)m * K_DIM + win * 64 + c * 8);
    float4 v0 = s4[0], v1 = s4[1];
    uint4 o;
    o.x = pkbf(v0.x, v0.y);
    o.y = pkbf(v0.z, v0.w);
    o.z = pkbf(v1.x, v1.y);
    o.w = pkbf(v1.z, v1.w);
    ((uint4*)xbf)[oc] = o;
  } else if (b < 1536) {
    // xa = 2*(x @ lora_A) for one row m, padded [512,32] bf16.
    // COALESCED: thread t handles k = i*256 + t, so a wave's lA reads are 64
    // consecutive rows (4 KB contiguous) and x reads are coalesced.
    __shared__ float red[256 * 17];
    int m = b - 1024;
    f32x4 ac0 = 0.f, ac1 = 0.f, ac2 = 0.f, ac3 = 0.f;
#pragma unroll
    for (int i = 0; i < 16; ++i) {
      int k = i * 256 + t;
      float xk = x[(size_t)m * K_DIM + k];
      const f32x4* l4 = (const f32x4*)(lA + (size_t)k * 16);
      ac0 += xk * l4[0];
      ac1 += xk * l4[1];
      ac2 += xk * l4[2];
      ac3 += xk * l4[3];
    }
#pragma unroll
    for (int r = 0; r < 4; ++r) {
      red[t * 17 + r] = ac0[r];
      red[t * 17 + 4 + r] = ac1[r];
      red[t * 17 + 8 + r] = ac2[r];
      red[t * 17 + 12 + r] = ac3[r];
    }
    __syncthreads();
#pragma unroll
    for (int s = 128; s >= 16; s >>= 1) {
      if (t < s)
        for (int r = 0; r < 16; ++r) red[t * 17 + r] += red[(t + s) * 17 + r];
      __syncthreads();
    }
    if (t < 32) {
      float v = 0.f;
      if (t < 16) {
        for (int p = 0; p < 16; ++p) v += red[p * 17 + t];
        v *= 2.0f;  // SCALING
      }
      uint32_t u = __builtin_bit_cast(uint32_t, v);
      xap[(size_t)m * 32 + t] = (ushort_t)((u + 0x8000u) >> 16);
    }
  } else {
    // Bt = lora_B^T, padded [11008,32] bf16
    int o = (b - 1536) * 256 + t;
    uint32_t p[8];
#pragma unroll
    for (int j = 0; j < 8; ++j)
      p[j] = pkbf(lB[(size_t)(2 * j) * N_OUT + o], lB[(size_t)(2 * j + 1) * N_OUT + o]);
    uint4* dst = reinterpret_cast<uint4*>(btp + (size_t)o * 32);
    dst[0] = make_uint4(p[0], p[1], p[2], p[3]);
    dst[1] = make_uint4(p[4], p[5], p[6], p[7]);
    dst[2] = make_uint4(0u, 0u, 0u, 0u);
    dst[3] = make_uint4(0u, 0u, 0u, 0u);
  }
}

// =============== main fused GEMM (split-K=2, atomic epilogue) ===============
// EXACT R0 structure (the unbeaten 137.7 us baseline): two __syncthreads per
// tile, compiler-scheduled. Only change: out is pre-ZEROED by memset and the
// kh==1 block initializes its accumulator with bias (instead of a separate
// 5504-block bias-broadcast in k_prep).
// BM=256 x BN=64, BK=64, 4 waves; wave w owns rows [w*64, w*64+64), acc 4x4.
__launch_bounds__(256, 3)
__global__ void k_main(const ushort_t* __restrict__ xbf, const int* __restrict__ wi,
                       const float* __restrict__ sc, const ushort_t* __restrict__ xap,
                       const ushort_t* __restrict__ btp,
                       const float* __restrict__ bias, float* __restrict__ out) {
  __shared__ __align__(16) ushort_t lds_a[BM * BK];  // 32 KB, [row][c'], swizzled
  __shared__ __align__(16) ushort_t lds_b[BN * 72];  // 9 KB, +8 pad
  __shared__ float2 lutp[256];                       // pair LUT, 2 KB

  const int t = threadIdx.x;
  const int lane = t & 63;
  const int w = t >> 6;
  const int o0 = blockIdx.x * BN;
  const int m0 = blockIdx.y * BM;
  const int kh = blockIdx.z;
  const int k0 = kh * KHALF;

  lutp[t] = make_float2(c_nf4[t & 15], c_nf4[t >> 4]);

  // B staging: thread -> (row=t>>2, 16 ints at (t&3)*16)
  const int brow = t >> 2, bq = t & 3;
  const int* gb = wi + (size_t)(o0 + brow) * K_DIM + k0 + bq * 16;
  const float* gs = sc + (size_t)(o0 + brow) * 64 + kh * 32;  // 1 scale/row/tile
  ushort_t* lb = lds_b + brow * 72 + bq * 16;

  // A DMA: wave w stages its own rows [w*64, w*64+64); 8 instrs x 1KB
  const ushort_t* ga =
      xbf + (size_t)(m0 + w * 64 + (lane >> 3)) * K_DIM + k0 + (lane & 7) * 8;
  ushort_t* la_dst = lds_a + w * 4096 + lane * 8;

  // acc init: kh==1 carries the bias (out itself is zero-filled by memset)
  const int cl = lane & 15;
  f32x4 acc[4][4];
#pragma unroll
  for (int ni = 0; ni < 4; ++ni) {
    float b0 = (kh == 1) ? bias[o0 + ni * 16 + cl] : 0.f;
#pragma unroll
    for (int mi = 0; mi < 4; ++mi) acc[mi][ni] = (f32x4){b0, b0, b0, b0};
  }

  // prologue: prefetch tile 0 indices + scale
  int4 bi0 = ((const int4*)gb)[0], bi1 = ((const int4*)gb)[1];
  int4 bi2 = ((const int4*)gb)[2], bi3 = ((const int4*)gb)[3];
  float s = gs[0];
  gb += BK;
  uint4 braw;

  const ushort_t* afb = lds_a + (w * 64 + (lane & 15)) * BK;
  const int q = lane >> 4;
  const ushort_t* bfb = lds_b + (lane & 15) * 72 + q * 8;

#pragma unroll 1
  for (int kt = 0; kt < NT; ++kt) {
    __syncthreads();  // prev tile's frag reads done (covers LUT init at kt=0)
    // dequant 16 idx -> 16 bf16 via pair LUT, 2x ds_write_b128
    uint4 w0, w1;
    w0.x = dq2(bi0.x, bi0.y, s, lutp);
    w0.y = dq2(bi0.z, bi0.w, s, lutp);
    w0.z = dq2(bi1.x, bi1.y, s, lutp);
    w0.w = dq2(bi1.z, bi1.w, s, lutp);
    w1.x = dq2(bi2.x, bi2.y, s, lutp);
    w1.y = dq2(bi2.z, bi2.w, s, lutp);
    w1.z = dq2(bi3.x, bi3.y, s, lutp);
    w1.w = dq2(bi3.z, bi3.w, s, lutp);
    *reinterpret_cast<uint4*>(lb) = w0;
    *reinterpret_cast<uint4*>(lb + 8) = w1;
    // A DMA for this tile (own wave's rows only)
#pragma unroll
    for (int j = 0; j < 8; ++j)
      async16(ga + (size_t)j * 8 * K_DIM + kt * BK, la_dst + j * 512);
    __syncthreads();  // drains DMA + makes lds_b visible
    // prefetch next tile (in flight during MFMA phase)
    if (kt + 1 < NT) {
      bi0 = ((const int4*)gb)[0];
      bi1 = ((const int4*)gb)[1];
      bi2 = ((const int4*)gb)[2];
      bi3 = ((const int4*)gb)[3];
      s = gs[kt + 1];
      gb += BK;
    } else if (kh == 1) {
      braw = *reinterpret_cast<const uint4*>(btp + (size_t)(o0 + brow) * 32 + bq * 8);
    }
    // fragments + 32 MFMA
#pragma unroll
    for (int kc = 0; kc < 2; ++kc) {
      const int cpr = ((kc * 4 + q) ^ (lane & 7)) * 8;  // un-swizzle
      bf16x8 av[4], bv[4];
#pragma unroll
      for (int mi = 0; mi < 4; ++mi) av[mi] = ldfrag(afb + mi * 16 * BK + cpr);
#pragma unroll
      for (int ni = 0; ni < 4; ++ni) bv[ni] = ldfrag(bfb + ni * 16 * 72 + kc * 32);
#pragma unroll
      for (int mi = 0; mi < 4; ++mi)
#pragma unroll
        for (int ni = 0; ni < 4; ++ni)
          acc[mi][ni] = __builtin_amdgcn_mfma_f32_16x16x32_bf16(av[mi], bv[ni],
                                                                acc[mi][ni], 0, 0, 0);
    }
  }

  // LoRA K-extension tail (kh==1 only): BK=32, A from xap, B from btp
  if (kh == 1) {
    __syncthreads();
    *reinterpret_cast<uint4*>(lds_b + brow * 72 + bq * 8) = braw;
#pragma unroll
    for (int j = 0; j < 4; ++j)
      async16(xap + (size_t)(m0 + w * 64 + j * 16 + (lane >> 2)) * 32 + (lane & 3) * 8,
              lds_a + w * 2048 + j * 512 + lane * 8);
    __syncthreads();
    bf16x8 av[4], bv[4];
#pragma unroll
    for (int mi = 0; mi < 4; ++mi)
      av[mi] = ldfrag(lds_a + w * 2048 + (mi * 16 + (lane & 15)) * 32 + q * 8);
#pragma unroll
    for (int ni = 0; ni < 4; ++ni)
      bv[ni] = ldfrag(lds_b + (ni * 16 + (lane & 15)) * 72 + q * 8);
#pragma unroll
    for (int mi = 0; mi < 4; ++mi)
#pragma unroll
      for (int ni = 0; ni < 4; ++ni)
        acc[mi][ni] = __builtin_amdgcn_mfma_f32_16x16x32_bf16(av[mi], bv[ni],
                                                              acc[mi][ni], 0, 0, 0);
  }

  // epilogue: atomic add onto zero-initialized out
  const int rg = q * 4;
#pragma unroll
  for (int ni = 0; ni < 4; ++ni) {
    int col = o0 + ni * 16 + cl;
#pragma unroll
    for (int mi = 0; mi < 4; ++mi) {
      int row0 = m0 + w * 64 + mi * 16 + rg;
      float* op = out + (size_t)row0 * N_OUT + col;
#pragma unroll
      for (int i = 0; i < 4; ++i) atomicAdd(op + (size_t)i * N_OUT, acc[mi][ni][i]);
    }
  }
}

extern "C" void kernel_launch(void* const* d_in, const int* in_sizes, int n_in,
                              void* d_out, int out_size, void* d_ws, size_t ws_size,
                              hipStream_t stream) {
  const float* x = (const float*)d_in[0];
  const int* wi = (const int*)d_in[1];
  const float* sc = (const float*)d_in[2];
  const float* lA = (const float*)d_in[3];
  const float* lB = (const float*)d_in[4];
  const float* bias = (const float*)d_in[5];
  float* out = (float*)d_out;

  char* wsb = (char*)d_ws;
  ushort_t* xbf = (ushort_t*)wsb;                               // 4 MB
  ushort_t* xap = (ushort_t*)(wsb + (4u << 20));                // 32 KB
  ushort_t* btp = (ushort_t*)(wsb + (4u << 20) + (32u << 10));  // 704 KB

  hipMemsetAsync(out, 0, (size_t)out_size, stream);  // replaces bias-broadcast
  k_prep<<<1579, 256, 0, stream>>>(x, lA, lB, xbf, xap, btp);
  dim3 grid(N_OUT / BN, M_DIM / BM, 2);
  k_main<<<grid, 256, 0, stream>>>(xbf, wi, sc, xap, btp, bias, out);
}